// Round 4
// baseline (250.306 us; speedup 1.0000x reference)
//
#include <hip/hip_runtime.h>
#include <hip/hip_bf16.h>

typedef __attribute__((ext_vector_type(8))) short short8;   // 8 bf16 (4 VGPRs) MFMA frag
typedef __attribute__((ext_vector_type(4))) float f32x4;

#define Bb 64
#define Cc 64
#define Tt 32
#define Nn 64
#define Kk 3
#define PITCH 72                      // u16 row pitch: 16B-aligned, bank stride 4 (<=2-way = free)
#define OUT_A_OFF 8388608L            // B*C*T*N floats of x_out, then A copy

__device__ __forceinline__ short f2bf(float f) {
    __hip_bfloat16 h = __float2bfloat16(f);
    return *reinterpret_cast<short*>(&h);
}

// One block per (b,t), 256 threads = 4 waves, 8 blocks/CU (18.7 KB LDS, <=64 VGPR).
// step1: x1(64x64) = W @ x        (bf16 MFMA, W-frags straight from global)
// per k: A_norm = (A+I)*dinv*dinv^T  from registers; A(k+1) load issued early
// step3: out += x1 @ A_norm       (bf16 MFMA)
// fused: verbatim fp32 copy of A slab into out[OUT_A_OFF..] (nontemporal).
__global__ __launch_bounds__(256, 8) void ctg_kernel(
    const float* __restrict__ X,
    const float* __restrict__ A,
    const float* __restrict__ W,
    const float* __restrict__ bias,
    float* __restrict__ out)
{
    __shared__ __align__(16) short buf1[Nn * PITCH];  // x^T[n][cin] -> x1[c][n]
    __shared__ __align__(16) short buf0[Nn * PITCH];  // A_norm^T[m][n]
    __shared__ float sDinv[Nn];

    const int tid = threadIdx.x;
    const int b = blockIdx.x >> 5;      // T = 32
    const int t = blockIdx.x & 31;
    const int l  = tid & 63;
    const int w  = tid >> 6;            // wave id -> output row stripe
    const int lr = l & 15;              // MFMA: A-row m / B-col n / C-col
    const int lq = l >> 4;              // MFMA quad

    const long xbase  = (long)b * (Cc * Tt * Nn) + (long)t * Nn;          // + c*2048 + n
    const long Abase0 = (long)b * (Kk * Tt * Nn * Nn) + (long)t * (Nn * Nn);
    const float* Aptr = A + Abase0 + 4 * tid;

    // ---- issue A(k=0) load first: latency overlaps staging + step1 ----
    f32x4 av[4];
    #pragma unroll
    for (int e = 0; e < 4; ++e) av[e] = *(const f32x4*)(Aptr + 1024 * e);

    // ---- stage x^T (bf16) into buf1 ----
    #pragma unroll
    for (int j = 0; j < 4; ++j) {
        int q  = tid + 256 * j;          // 0..1023 float4s
        int r  = q >> 4;                 // cin
        int c0 = (q & 15) * 4;           // n start
        f32x4 xv = *(const f32x4*)(X + xbase + (long)r * (Tt * Nn) + c0);
        #pragma unroll
        for (int i = 0; i < 4; ++i) buf1[(c0 + i) * PITCH + r] = f2bf(xv[i]);
    }

    // ---- W fragments straight from global (16 KB, L2-resident) ----
    const float* wrow = W + (16 * w + lr) * 64 + 8 * lq;
    f32x4 w00 = *(const f32x4*)(wrow);
    f32x4 w01 = *(const f32x4*)(wrow + 4);
    f32x4 w10 = *(const f32x4*)(wrow + 32);
    f32x4 w11 = *(const f32x4*)(wrow + 36);
    short8 aw0, aw1;
    #pragma unroll
    for (int i = 0; i < 4; ++i) {
        aw0[i] = f2bf(w00[i]); aw0[4 + i] = f2bf(w01[i]);
        aw1[i] = f2bf(w10[i]); aw1[4 + i] = f2bf(w11[i]);
    }
    f32x4 bv = *(const f32x4*)(bias + 16 * w + 4 * lq);

    __syncthreads();   // x^T staged

    // ---- step 1: x1 = W @ x ----
    f32x4 acc1[4];
    #pragma unroll
    for (int nt = 0; nt < 4; ++nt) {
        acc1[nt] = (f32x4){0.f, 0.f, 0.f, 0.f};
        short8 b0 = *(const short8*)&buf1[(16 * nt + lr) * PITCH + 8 * lq];
        short8 b1 = *(const short8*)&buf1[(16 * nt + lr) * PITCH + 32 + 8 * lq];
        acc1[nt] = __builtin_amdgcn_mfma_f32_16x16x32_bf16(aw0, b0, acc1[nt], 0, 0, 0);
        acc1[nt] = __builtin_amdgcn_mfma_f32_16x16x32_bf16(aw1, b1, acc1[nt], 0, 0, 0);
    }
    __syncthreads();   // all step1 reads of buf1 done

    // write x1 (+bias) into buf1, A-op layout; C/D layout: row=4*lq+r, col=lr
    #pragma unroll
    for (int nt = 0; nt < 4; ++nt)
        #pragma unroll
        for (int r = 0; r < 4; ++r) {
            int c = 16 * w + 4 * lq + r;
            buf1[c * PITCH + 16 * nt + lr] = f2bf(acc1[nt][r] + bv[r]);
        }

    f32x4 acc3[4];
    #pragma unroll
    for (int mt = 0; mt < 4; ++mt) acc3[mt] = (f32x4){0.f, 0.f, 0.f, 0.f};

    const int m0 = (tid & 15) * 4;       // owned column block during normalize
    const int nrow = tid >> 4;           // owned rows: nrow + 16e

    for (int k = 0; k < Kk; ++k) {
        const long Ab = Abase0 + (long)k * (Tt * Nn * Nn);

        // fused verbatim copy of A (nontemporal: write-once stream)
        #pragma unroll
        for (int e = 0; e < 4; ++e)
            __builtin_nontemporal_store(av[e], (f32x4*)(out + OUT_A_OFF + Ab + 4 * (tid + 256 * e)));

        // row-sum via 16-lane butterfly: element (e,i) is A[nrow+16e][m0+i]
        #pragma unroll
        for (int e = 0; e < 4; ++e) {
            float q = av[e][0] + av[e][1] + av[e][2] + av[e][3];
            q += __shfl_xor(q, 1);
            q += __shfl_xor(q, 2);
            q += __shfl_xor(q, 4);
            q += __shfl_xor(q, 8);
            if ((tid & 15) == 0) sDinv[nrow + 16 * e] = rsqrtf(q + 1.0f);  // deg(A+I)
        }
        __syncthreads();   // B2: sDinv ready; prev step3 reads of buf0 complete

        // normalize from registers, store transposed bf16 (B-op layout)
        float dm[4] = { sDinv[m0], sDinv[m0 + 1], sDinv[m0 + 2], sDinv[m0 + 3] };
        #pragma unroll
        for (int e = 0; e < 4; ++e) {
            int n = nrow + 16 * e;
            float dn = sDinv[n];
            #pragma unroll
            for (int i = 0; i < 4; ++i) {
                float v = av[e][i];
                if (m0 + i == n) v += 1.0f;                  // renormalization trick: A + I
                buf0[(m0 + i) * PITCH + n] = f2bf(v * dn * dm[i]);
            }
        }

        // prefetch A(k+1): latency overlaps B3 + step3
        if (k + 1 < Kk) {
            #pragma unroll
            for (int e = 0; e < 4; ++e)
                av[e] = *(const f32x4*)(Aptr + (k + 1) * (Tt * Nn * Nn) + 1024 * e);
        }
        __syncthreads();   // B3: buf0 (A_norm^T) ready

        // ---- step 3: acc3 += x1 @ A_norm ----
        short8 a0 = *(const short8*)&buf1[(16 * w + lr) * PITCH + 8 * lq];
        short8 a1 = *(const short8*)&buf1[(16 * w + lr) * PITCH + 32 + 8 * lq];
        #pragma unroll
        for (int mt = 0; mt < 4; ++mt) {
            short8 b0 = *(const short8*)&buf0[(16 * mt + lr) * PITCH + 8 * lq];
            short8 b1 = *(const short8*)&buf0[(16 * mt + lr) * PITCH + 32 + 8 * lq];
            acc3[mt] = __builtin_amdgcn_mfma_f32_16x16x32_bf16(a0, b0, acc3[mt], 0, 0, 0);
            acc3[mt] = __builtin_amdgcn_mfma_f32_16x16x32_bf16(a1, b1, acc3[mt], 0, 0, 0);
        }
    }

    // ---- store x_out fp32; C/D layout row=4*lq+r (c), col=lr (m) ----
    #pragma unroll
    for (int mt = 0; mt < 4; ++mt)
        #pragma unroll
        for (int r = 0; r < 4; ++r) {
            int c = 16 * w + 4 * lq + r;
            __builtin_nontemporal_store(acc3[mt][r],
                out + xbase + (long)c * (Tt * Nn) + 16 * mt + lr);
        }
}

extern "C" void kernel_launch(void* const* d_in, const int* in_sizes, int n_in,
                              void* d_out, int out_size, void* d_ws, size_t ws_size,
                              hipStream_t stream) {
    const float* X    = (const float*)d_in[0];
    const float* A    = (const float*)d_in[1];
    const float* W    = (const float*)d_in[2];
    const float* bias = (const float*)d_in[3];
    float* out = (float*)d_out;
    ctg_kernel<<<dim3(Bb * Tt), dim3(256), 0, stream>>>(X, A, W, bias, out);
}